// Round 20
// baseline (128.549 us; speedup 1.0000x reference)
//
#include <hip/hip_runtime.h>
#include <cstdint>
#include <cstddef>

// GlobalAttention (Luong 'general'): q = src@W^T ; x = q@MB^T ; softmax(mask) ; c = P@MB
// Outputs: d_out = [ c (8*1024*256) | align_vectors (8*1024*4096) ] fp32.
// Pipeline: k_qproj -> k_logits7 -> k_pv (fused row-stats) -> k_csum
//
// R20 = R19 (122.85us best) + last micro-lever: pc split-K partials become a
// fully NONTEMPORAL stream (pv nt-stores half8, csum nt-loads) so the 32 MB
// pc round-trip doesn't evict pv's mbank/x working set or csum's align lines.
// Everything else frozen byte-for-byte from R19.

typedef _Float16 f16;
typedef _Float16 half8 __attribute__((ext_vector_type(8)));
typedef _Float16 half4v __attribute__((ext_vector_type(4)));
typedef float f32x4 __attribute__((ext_vector_type(4)));

#define MFMA16(a, b, c) __builtin_amdgcn_mfma_f32_16x16x32_f16((a), (b), (c), 0, 0, 0)

static constexpr int NBATCH = 8;
static constexpr int NT = 1024;   // TGT
static constexpr int NS = 4096;   // SRC
static constexpr int ND = 256;    // SDIM == TDIM
static constexpr float NEGBIG = -3.0e38f;

__device__ __forceinline__ int swz(int row, int byteInRow) {
  return byteInRow ^ ((row & 7) << 4);
}

// ---------------- K1: q16 = source @ W^T (fp16 out) ---------------- (frozen)
__global__ __launch_bounds__(256) void k_qproj(const float* __restrict__ src,
                                               const float* __restrict__ W,
                                               f16* __restrict__ q16) {
  __shared__ __align__(16) f16 As[64 * 64];
  __shared__ __align__(16) f16 Bs[256 * 64];
  const int tid = threadIdx.x;
  const int w = tid >> 6, l = tid & 63;
  const int wt = w >> 1, wn = w & 1;
  const int q = l >> 4, lc = l & 15;
  const int t0 = blockIdx.x * 64;

  f32x4 acc[2][8];
#pragma unroll
  for (int i = 0; i < 2; ++i)
#pragma unroll
    for (int j = 0; j < 8; ++j) acc[i][j] = (f32x4){0.f, 0.f, 0.f, 0.f};

  for (int k0 = 0; k0 < 256; k0 += 64) {
    __syncthreads();
    {
      const int r = tid >> 2, c2 = (tid & 3) * 2;
      const float* g = src + (size_t)(t0 + r) * 256 + k0 + c2 * 8;
      float4 f0 = ((const float4*)g)[0], f1 = ((const float4*)g)[1];
      float4 f2 = ((const float4*)g)[2], f3 = ((const float4*)g)[3];
      half8 h0 = {(f16)f0.x, (f16)f0.y, (f16)f0.z, (f16)f0.w,
                  (f16)f1.x, (f16)f1.y, (f16)f1.z, (f16)f1.w};
      half8 h1 = {(f16)f2.x, (f16)f2.y, (f16)f2.z, (f16)f2.w,
                  (f16)f3.x, (f16)f3.y, (f16)f3.z, (f16)f3.w};
      *(half8*)((char*)As + r * 128 + swz(r, c2 * 16)) = h0;
      *(half8*)((char*)As + r * 128 + swz(r, c2 * 16 + 16)) = h1;
    }
    {
      const int n = tid;
      const float* g = W + (size_t)n * 256 + k0;
#pragma unroll
      for (int c = 0; c < 8; ++c) {
        float4 f0 = ((const float4*)(g + c * 8))[0];
        float4 f1 = ((const float4*)(g + c * 8))[1];
        half8 h = {(f16)f0.x, (f16)f0.y, (f16)f0.z, (f16)f0.w,
                   (f16)f1.x, (f16)f1.y, (f16)f1.z, (f16)f1.w};
        *(half8*)((char*)Bs + n * 128 + swz(n, c * 16)) = h;
      }
    }
    __syncthreads();
    half8 a[2][2], bb[8][2];
#pragma unroll
    for (int mb = 0; mb < 2; ++mb)
#pragma unroll
      for (int kf = 0; kf < 2; ++kf) {
        const int r = wt * 32 + mb * 16 + lc;
        a[mb][kf] = *(const half8*)((const char*)As + r * 128 + swz(r, kf * 64 + q * 16));
      }
#pragma unroll
    for (int nb = 0; nb < 8; ++nb)
#pragma unroll
      for (int kf = 0; kf < 2; ++kf) {
        const int r = wn * 128 + nb * 16 + lc;
        bb[nb][kf] = *(const half8*)((const char*)Bs + r * 128 + swz(r, kf * 64 + q * 16));
      }
#pragma unroll
    for (int kf = 0; kf < 2; ++kf)
#pragma unroll
      for (int mb = 0; mb < 2; ++mb)
#pragma unroll
        for (int nb = 0; nb < 8; ++nb)
          acc[mb][nb] = MFMA16(a[mb][kf], bb[nb][kf], acc[mb][nb]);
  }
#pragma unroll
  for (int mb = 0; mb < 2; ++mb)
#pragma unroll
    for (int nb = 0; nb < 8; ++nb)
#pragma unroll
      for (int j = 0; j < 4; ++j) {
        const int t = t0 + wt * 32 + mb * 16 + q * 4 + j;
        const int n = wn * 128 + nb * 16 + lc;
        q16[(size_t)t * 256 + n] = (f16)acc[mb][nb][j];
      }
}

// ---------------- K2: stage-once barrier-free QK + setprio ---------------- (frozen)
__global__ __launch_bounds__(512, 2) void k_logits7(const float* __restrict__ mbank,
                                                    const f16* __restrict__ q16,
                                                    const int* __restrict__ mask,
                                                    float* __restrict__ alignv,
                                                    float* __restrict__ pstats,
                                                    f16* __restrict__ xh16) {
  __shared__ __align__(16) f16 Bs[64 * 256];  // [s][d] f16, 512B rows, swz (32 KB)
  const int tid = threadIdx.x;
  const int w = tid >> 6, l = tid & 63;
  const int q = l >> 4, lc = l & 15;
  const int bid = blockIdx.x;
  const int b = bid & 7;
  const int kc = bid >> 3;  // 0..63
  const int s0 = kc * 64;

  {  // stage Bs[64][256] fp32 -> f16, once
    const int r = tid >> 3;
    const int c0 = (tid & 7) * 32;
    const float4* g = (const float4*)(mbank + ((size_t)b * NS + s0 + r) * ND + c0);
    float4 f[8];
#pragma unroll
    for (int i = 0; i < 8; ++i) f[i] = g[i];
#pragma unroll
    for (int i = 0; i < 4; ++i) {
      half8 h = {(f16)f[2 * i].x, (f16)f[2 * i].y, (f16)f[2 * i].z, (f16)f[2 * i].w,
                 (f16)f[2 * i + 1].x, (f16)f[2 * i + 1].y, (f16)f[2 * i + 1].z,
                 (f16)f[2 * i + 1].w};
      *(half8*)((char*)Bs + r * 512 + swz(r, c0 * 2 + i * 16)) = h;
    }
  }
  int4 mk[4];
#pragma unroll
  for (int nb = 0; nb < 4; ++nb)
    mk[nb] = *(const int4*)(mask + (size_t)b * NS + s0 + nb * 16 + q * 4);
  __syncthreads();  // Bs read-only from here: no further barriers

  for (int p = 0; p < 8; ++p) {
    const int trow = p * 128 + w * 16 + lc;
    half8 aq[8];
    {
      const f16* qrow = q16 + (size_t)(b * NT + trow) * 256;
#pragma unroll
      for (int kf = 0; kf < 8; ++kf)
        aq[kf] = *(const half8*)(qrow + kf * 32 + q * 8);
    }
    f32x4 xT[4];
#pragma unroll
    for (int i = 0; i < 4; ++i) xT[i] = (f32x4){0.f, 0.f, 0.f, 0.f};
    __builtin_amdgcn_s_setprio(1);  // T5
#pragma unroll
    for (int kf = 0; kf < 8; ++kf)
#pragma unroll
      for (int nb = 0; nb < 4; ++nb) {
        const int rs = nb * 16 + lc;
        half8 mbf = *(const half8*)((const char*)Bs + rs * 512 + swz(rs, kf * 64 + q * 16));
        xT[nb] = MFMA16(mbf, aq[kf], xT[nb]);
      }
    __builtin_amdgcn_s_setprio(0);
    float v[4][4];
    float vmax = NEGBIG;
#pragma unroll
    for (int nb = 0; nb < 4; ++nb) {
      v[nb][0] = mk[nb].x ? xT[nb][0] : NEGBIG;
      v[nb][1] = mk[nb].y ? xT[nb][1] : NEGBIG;
      v[nb][2] = mk[nb].z ? xT[nb][2] : NEGBIG;
      v[nb][3] = mk[nb].w ? xT[nb][3] : NEGBIG;
      vmax = fmaxf(vmax, fmaxf(fmaxf(v[nb][0], v[nb][1]), fmaxf(v[nb][2], v[nb][3])));
    }
    vmax = fmaxf(vmax, __shfl_xor(vmax, 16));
    vmax = fmaxf(vmax, __shfl_xor(vmax, 32));
    float vsum = 0.f;
    if (xh16) {
      f16* xr = xh16 + (size_t)(b * NT + trow) * NS + s0;
#pragma unroll
      for (int nb = 0; nb < 4; ++nb) {
        float e0 = __expf(v[nb][0] - vmax), e1 = __expf(v[nb][1] - vmax);
        float e2 = __expf(v[nb][2] - vmax), e3 = __expf(v[nb][3] - vmax);
        vsum += e0 + e1 + e2 + e3;
        half4v hv = {(f16)e0, (f16)e1, (f16)e2, (f16)e3};
        *(half4v*)(xr + nb * 16 + q * 4) = hv;
      }
    } else {
      float* ab = alignv + ((size_t)b * NT + trow) * NS + s0;
#pragma unroll
      for (int nb = 0; nb < 4; ++nb) {
        *(f32x4*)(ab + nb * 16 + q * 4) = (f32x4){v[nb][0], v[nb][1], v[nb][2], v[nb][3]};
        vsum += __expf(v[nb][0] - vmax) + __expf(v[nb][1] - vmax) +
                __expf(v[nb][2] - vmax) + __expf(v[nb][3] - vmax);
      }
    }
    vsum += __shfl_xor(vsum, 16);
    vsum += __shfl_xor(vsum, 32);
    if (l < 16) {
      pstats[((size_t)(b * NT + trow) * 64 + kc) * 2 + 0] = vmax;
      pstats[((size_t)(b * NT + trow) * 64 + kc) * 2 + 1] = vsum;
    }
  }
}

// ---------------- K3: p ; partial c = P@V + fused row-stats + setprio ----
__global__ __launch_bounds__(512, 4) void k_pv(const float* __restrict__ mbank,
                                               const float* __restrict__ pstats,
                                               float* __restrict__ alignv,
                                               f16* __restrict__ pc,
                                               const f16* __restrict__ xh16) {
  __shared__ __align__(16) f16 VT[256 * 64];
  __shared__ __align__(16) f16 Ps[64 * 64];
  const int tid = threadIdx.x;
  const int w = tid >> 6, l = tid & 63;
  const int wtg = w >> 2, wd = w & 3;
  const int q = l >> 4, lc = l & 15;
  const int bid = blockIdx.x;
  const int b = bid & 7;
  const int kc = (bid >> 3) & 3;
  const int tt = bid >> 5;
  const int t0 = tt * 64;
  const int s0 = kc * 1024;

  const int pt = tid >> 3;
  const int ps8 = (tid & 7) * 8;
  const size_t rowg = (size_t)b * NT + t0 + pt;

  // fused row-stats: 8 threads per row reduce 64 chunk partials
  float mv, lv;
  {
    const float* pr = pstats + (rowg * 64 + (size_t)(tid & 7) * 8) * 2;
    float4 a0 = ((const float4*)pr)[0];
    float4 a1 = ((const float4*)pr)[1];
    float4 a2 = ((const float4*)pr)[2];
    float4 a3 = ((const float4*)pr)[3];
    float mloc = fmaxf(fmaxf(a0.x, a0.z), fmaxf(a1.x, a1.z));
    mloc = fmaxf(mloc, fmaxf(fmaxf(a2.x, a2.z), fmaxf(a3.x, a3.z)));
    mloc = fmaxf(mloc, __shfl_xor(mloc, 1));
    mloc = fmaxf(mloc, __shfl_xor(mloc, 2));
    mloc = fmaxf(mloc, __shfl_xor(mloc, 4));
    float s = a0.y * __expf(a0.x - mloc) + a0.w * __expf(a0.z - mloc) +
              a1.y * __expf(a1.x - mloc) + a1.w * __expf(a1.z - mloc) +
              a2.y * __expf(a2.x - mloc) + a2.w * __expf(a2.z - mloc) +
              a3.y * __expf(a3.x - mloc) + a3.w * __expf(a3.z - mloc);
    s += __shfl_xor(s, 1);
    s += __shfl_xor(s, 2);
    s += __shfl_xor(s, 4);
    mv = mloc;
    lv = (s > 0.f) ? (1.f / s) : 0.f;
  }

  float* xrow = alignv + rowg * NS + s0 + ps8;
  const f16* hrow = xh16 ? (xh16 + rowg * NS + s0 + ps8) : nullptr;
  const float* prow = pstats + (rowg * 64 + kc * 16) * 2;

  f32x4 acc[2][4];
#pragma unroll
  for (int i = 0; i < 2; ++i)
#pragma unroll
    for (int j = 0; j < 4; ++j) acc[i][j] = (f32x4){0.f, 0.f, 0.f, 0.f};

  const int dstage = (w & 3) * 64 + l;
  const int shalf = (w >> 2) * 32;

  float4 xA, xB;
  half8 hx;
  if (xh16) {
    hx = *(const half8*)(hrow);
  } else {
    xA = ((const float4*)xrow)[0];
    xB = ((const float4*)xrow)[1];
  }

  for (int st = 0; st < 16; ++st) {
    const int sb = s0 + st * 64;
    __syncthreads();
    {
#pragma unroll
      for (int i = 0; i < 8; ++i) {
        const int s4 = shalf + i * 4;
        const float* g = mbank + ((size_t)b * NS + sb + s4) * ND + dstage;
        const float f0 = g[0], f1 = g[ND], f2 = g[2 * ND], f3 = g[3 * ND];
        half4v h = {(f16)f0, (f16)f1, (f16)f2, (f16)f3};
        *(half4v*)((char*)VT + dstage * 128 + swz(dstage, s4 * 2)) = h;
      }
    }
    {
      float p0, p1, p2, p3, p4, p5, p6, p7;
      if (xh16) {
        const float scale = __expf(prow[st * 2] - mv) * lv;
        p0 = (float)hx[0] * scale; p1 = (float)hx[1] * scale;
        p2 = (float)hx[2] * scale; p3 = (float)hx[3] * scale;
        p4 = (float)hx[4] * scale; p5 = (float)hx[5] * scale;
        p6 = (float)hx[6] * scale; p7 = (float)hx[7] * scale;
      } else {
        p0 = __expf(xA.x - mv) * lv; p1 = __expf(xA.y - mv) * lv;
        p2 = __expf(xA.z - mv) * lv; p3 = __expf(xA.w - mv) * lv;
        p4 = __expf(xB.x - mv) * lv; p5 = __expf(xB.y - mv) * lv;
        p6 = __expf(xB.z - mv) * lv; p7 = __expf(xB.w - mv) * lv;
      }
      float* xp = xrow + st * 64;
      f32x4 s0v = {p0, p1, p2, p3};
      f32x4 s1v = {p4, p5, p6, p7};
      __builtin_nontemporal_store(s0v, (f32x4*)xp);
      __builtin_nontemporal_store(s1v, (f32x4*)(xp + 4));
      half8 h = {(f16)p0, (f16)p1, (f16)p2, (f16)p3,
                 (f16)p4, (f16)p5, (f16)p6, (f16)p7};
      *(half8*)((char*)Ps + pt * 128 + swz(pt, ps8 * 2)) = h;
    }
    if (st < 15) {
      if (xh16) {
        hx = *(const half8*)(hrow + (st + 1) * 64);
      } else {
        const float* xn = xrow + (st + 1) * 64;
        xA = ((const float4*)xn)[0];
        xB = ((const float4*)xn)[1];
      }
    }
    __syncthreads();
    half8 a[2][2];
#pragma unroll
    for (int mb = 0; mb < 2; ++mb)
#pragma unroll
      for (int kf = 0; kf < 2; ++kf) {
        const int r = wtg * 32 + mb * 16 + lc;
        a[mb][kf] = *(const half8*)((const char*)Ps + r * 128 + swz(r, kf * 64 + q * 16));
      }
    __builtin_amdgcn_s_setprio(1);  // T5
#pragma unroll
    for (int kf = 0; kf < 2; ++kf)
#pragma unroll
      for (int nb = 0; nb < 4; ++nb) {
        const int d = wd * 64 + nb * 16 + lc;
        half8 bbt = *(const half8*)((const char*)VT + d * 128 + swz(d, kf * 64 + q * 16));
#pragma unroll
        for (int mb = 0; mb < 2; ++mb)
          acc[mb][nb] = MFMA16(a[mb][kf], bbt, acc[mb][nb]);
      }
    __builtin_amdgcn_s_setprio(0);
  }

  // epilogue: nt half8 split-K partial stores (write-once stream)
#pragma unroll
  for (int mb = 0; mb < 2; ++mb)
#pragma unroll
    for (int nb = 0; nb < 4; ++nb) {
      const int j0 = 0;
      (void)j0;
#pragma unroll
      for (int j = 0; j < 4; ++j) {
        const int t = t0 + wtg * 32 + mb * 16 + q * 4 + j;
        const int d = wd * 64 + nb * 16 + lc;
        __builtin_nontemporal_store(
            (f16)acc[mb][nb][j],
            pc + (size_t)kc * ((size_t)NBATCH * NT * ND) + ((size_t)b * NT + t) * ND + d);
      }
    }
}

// ---------------- K4: c = sum of 4 fp16 split-K partials (nt loads) ----------
__global__ __launch_bounds__(256) void k_csum(const f16* __restrict__ pc,
                                              float* __restrict__ outc) {
  const size_t i8 = ((size_t)blockIdx.x * 256 + threadIdx.x) * 8;
  const size_t STRIDE = (size_t)NBATCH * NT * ND;
  half8 a = __builtin_nontemporal_load((const half8*)(pc + i8));
  half8 b = __builtin_nontemporal_load((const half8*)(pc + STRIDE + i8));
  half8 c = __builtin_nontemporal_load((const half8*)(pc + 2 * STRIDE + i8));
  half8 d = __builtin_nontemporal_load((const half8*)(pc + 3 * STRIDE + i8));
  float4 r0, r1;
  r0.x = (float)a[0] + (float)b[0] + (float)c[0] + (float)d[0];
  r0.y = (float)a[1] + (float)b[1] + (float)c[1] + (float)d[1];
  r0.z = (float)a[2] + (float)b[2] + (float)c[2] + (float)d[2];
  r0.w = (float)a[3] + (float)b[3] + (float)c[3] + (float)d[3];
  r1.x = (float)a[4] + (float)b[4] + (float)c[4] + (float)d[4];
  r1.y = (float)a[5] + (float)b[5] + (float)c[5] + (float)d[5];
  r1.z = (float)a[6] + (float)b[6] + (float)c[6] + (float)d[6];
  r1.w = (float)a[7] + (float)b[7] + (float)c[7] + (float)d[7];
  *(float4*)(outc + i8) = r0;
  *(float4*)(outc + i8 + 4) = r1;
}

extern "C" void kernel_launch(void* const* d_in, const int* in_sizes, int n_in,
                              void* d_out, int out_size, void* d_ws, size_t ws_size,
                              hipStream_t stream) {
  const float* mbank = (const float*)d_in[0];  // (8,4096,256) f32
  const float* src   = (const float*)d_in[1];  // (8,1024,256) f32
  const int*   mask  = (const int*)d_in[2];    // (8,4096) bool->int
  const float* W     = (const float*)d_in[3];  // (256,256) f32

  float* out_c = (float*)d_out;
  float* out_align = out_c + (size_t)NBATCH * NT * ND;

  // ws layout:
  //   [0, 4 MB)          q16   : 8192x256 fp16
  //   [4 MB, 8 MB)       pstats: 8192x64x2 f32
  //   [8 MB, 24 MB)      pc    : 4 x 2M fp16 split-K partials
  //   [28 MB, 92 MB)     xh    : fp16 chunk-exponentials (if ws fits)
  char* ws = (char*)d_ws;
  f16* q16      = (f16*)ws;
  float* pstats = (float*)(ws + (4 << 20));
  f16* pc       = (f16*)(ws + (8 << 20));
  f16* xh16 = (ws_size >= ((size_t)92 << 20)) ? (f16*)(ws + (28 << 20)) : nullptr;

  hipLaunchKernelGGL(k_qproj, dim3(128), dim3(256), 0, stream, src, W, q16);
  hipLaunchKernelGGL(k_logits7, dim3(512), dim3(512), 0, stream,
                     mbank, q16, mask, out_align, pstats, xh16);
  hipLaunchKernelGGL(k_pv, dim3(512), dim3(512), 0, stream,
                     mbank, pstats, out_align, pc, (const f16*)xh16);
  hipLaunchKernelGGL(k_csum, dim3(1024), dim3(256), 0, stream, pc, out_c);
}

// Round 21
// 122.201 us; speedup vs baseline: 1.0519x; 1.0519x over previous
//
#include <hip/hip_runtime.h>
#include <cstdint>
#include <cstddef>

// GlobalAttention (Luong 'general'): q = src@W^T ; x = q@MB^T ; softmax(mask) ; c = P@MB
// Outputs: d_out = [ c (8*1024*256) | align_vectors (8*1024*4096) ] fp32.
// Pipeline: k_qproj -> k_logits7 -> k_pv (fused row-stats + nt p-store) -> k_csum
//
// FINAL (R21 = R19, the measured optimum at 122.85 us; R20's nt pc stream
// regressed to 128.5 via scalar 2-B nt stores -> reverted).
// Key techniques: fp16 MFMA with fp32 accumulate everywhere; stage-once
// barrier-free logits kernel (mbank chunk staged to LDS once, q16 re-read from
// L2); XCD-pinned batch mapping (b = bid&7); swapped-operand MFMA so x-stores
// are float4; T5 s_setprio around MFMA clusters; k_stats fused into k_pv
// prologue; nontemporal p-stores (pure output stream); fp16 split-K partials.

typedef _Float16 f16;
typedef _Float16 half8 __attribute__((ext_vector_type(8)));
typedef _Float16 half4v __attribute__((ext_vector_type(4)));
typedef float f32x4 __attribute__((ext_vector_type(4)));

#define MFMA16(a, b, c) __builtin_amdgcn_mfma_f32_16x16x32_f16((a), (b), (c), 0, 0, 0)

static constexpr int NBATCH = 8;
static constexpr int NT = 1024;   // TGT
static constexpr int NS = 4096;   // SRC
static constexpr int ND = 256;    // SDIM == TDIM
static constexpr float NEGBIG = -3.0e38f;

__device__ __forceinline__ int swz(int row, int byteInRow) {
  return byteInRow ^ ((row & 7) << 4);
}

// ---------------- K1: q16 = source @ W^T (fp16 out) ----------------
__global__ __launch_bounds__(256) void k_qproj(const float* __restrict__ src,
                                               const float* __restrict__ W,
                                               f16* __restrict__ q16) {
  __shared__ __align__(16) f16 As[64 * 64];
  __shared__ __align__(16) f16 Bs[256 * 64];
  const int tid = threadIdx.x;
  const int w = tid >> 6, l = tid & 63;
  const int wt = w >> 1, wn = w & 1;
  const int q = l >> 4, lc = l & 15;
  const int t0 = blockIdx.x * 64;

  f32x4 acc[2][8];
#pragma unroll
  for (int i = 0; i < 2; ++i)
#pragma unroll
    for (int j = 0; j < 8; ++j) acc[i][j] = (f32x4){0.f, 0.f, 0.f, 0.f};

  for (int k0 = 0; k0 < 256; k0 += 64) {
    __syncthreads();
    {
      const int r = tid >> 2, c2 = (tid & 3) * 2;
      const float* g = src + (size_t)(t0 + r) * 256 + k0 + c2 * 8;
      float4 f0 = ((const float4*)g)[0], f1 = ((const float4*)g)[1];
      float4 f2 = ((const float4*)g)[2], f3 = ((const float4*)g)[3];
      half8 h0 = {(f16)f0.x, (f16)f0.y, (f16)f0.z, (f16)f0.w,
                  (f16)f1.x, (f16)f1.y, (f16)f1.z, (f16)f1.w};
      half8 h1 = {(f16)f2.x, (f16)f2.y, (f16)f2.z, (f16)f2.w,
                  (f16)f3.x, (f16)f3.y, (f16)f3.z, (f16)f3.w};
      *(half8*)((char*)As + r * 128 + swz(r, c2 * 16)) = h0;
      *(half8*)((char*)As + r * 128 + swz(r, c2 * 16 + 16)) = h1;
    }
    {
      const int n = tid;
      const float* g = W + (size_t)n * 256 + k0;
#pragma unroll
      for (int c = 0; c < 8; ++c) {
        float4 f0 = ((const float4*)(g + c * 8))[0];
        float4 f1 = ((const float4*)(g + c * 8))[1];
        half8 h = {(f16)f0.x, (f16)f0.y, (f16)f0.z, (f16)f0.w,
                   (f16)f1.x, (f16)f1.y, (f16)f1.z, (f16)f1.w};
        *(half8*)((char*)Bs + n * 128 + swz(n, c * 16)) = h;
      }
    }
    __syncthreads();
    half8 a[2][2], bb[8][2];
#pragma unroll
    for (int mb = 0; mb < 2; ++mb)
#pragma unroll
      for (int kf = 0; kf < 2; ++kf) {
        const int r = wt * 32 + mb * 16 + lc;
        a[mb][kf] = *(const half8*)((const char*)As + r * 128 + swz(r, kf * 64 + q * 16));
      }
#pragma unroll
    for (int nb = 0; nb < 8; ++nb)
#pragma unroll
      for (int kf = 0; kf < 2; ++kf) {
        const int r = wn * 128 + nb * 16 + lc;
        bb[nb][kf] = *(const half8*)((const char*)Bs + r * 128 + swz(r, kf * 64 + q * 16));
      }
#pragma unroll
    for (int kf = 0; kf < 2; ++kf)
#pragma unroll
      for (int mb = 0; mb < 2; ++mb)
#pragma unroll
        for (int nb = 0; nb < 8; ++nb)
          acc[mb][nb] = MFMA16(a[mb][kf], bb[nb][kf], acc[mb][nb]);
  }
#pragma unroll
  for (int mb = 0; mb < 2; ++mb)
#pragma unroll
    for (int nb = 0; nb < 8; ++nb)
#pragma unroll
      for (int j = 0; j < 4; ++j) {
        const int t = t0 + wt * 32 + mb * 16 + q * 4 + j;
        const int n = wn * 128 + nb * 16 + lc;
        q16[(size_t)t * 256 + n] = (f16)acc[mb][nb][j];
      }
}

// ---------------- K2: stage-once barrier-free QK + setprio ----
__global__ __launch_bounds__(512, 2) void k_logits7(const float* __restrict__ mbank,
                                                    const f16* __restrict__ q16,
                                                    const int* __restrict__ mask,
                                                    float* __restrict__ alignv,
                                                    float* __restrict__ pstats,
                                                    f16* __restrict__ xh16) {
  __shared__ __align__(16) f16 Bs[64 * 256];  // [s][d] f16, 512B rows, swz (32 KB)
  const int tid = threadIdx.x;
  const int w = tid >> 6, l = tid & 63;
  const int q = l >> 4, lc = l & 15;
  const int bid = blockIdx.x;
  const int b = bid & 7;
  const int kc = bid >> 3;  // 0..63
  const int s0 = kc * 64;

  {  // stage Bs[64][256] fp32 -> f16, once
    const int r = tid >> 3;
    const int c0 = (tid & 7) * 32;
    const float4* g = (const float4*)(mbank + ((size_t)b * NS + s0 + r) * ND + c0);
    float4 f[8];
#pragma unroll
    for (int i = 0; i < 8; ++i) f[i] = g[i];
#pragma unroll
    for (int i = 0; i < 4; ++i) {
      half8 h = {(f16)f[2 * i].x, (f16)f[2 * i].y, (f16)f[2 * i].z, (f16)f[2 * i].w,
                 (f16)f[2 * i + 1].x, (f16)f[2 * i + 1].y, (f16)f[2 * i + 1].z,
                 (f16)f[2 * i + 1].w};
      *(half8*)((char*)Bs + r * 512 + swz(r, c0 * 2 + i * 16)) = h;
    }
  }
  int4 mk[4];
#pragma unroll
  for (int nb = 0; nb < 4; ++nb)
    mk[nb] = *(const int4*)(mask + (size_t)b * NS + s0 + nb * 16 + q * 4);
  __syncthreads();  // Bs read-only from here: no further barriers

  for (int p = 0; p < 8; ++p) {
    const int trow = p * 128 + w * 16 + lc;
    half8 aq[8];
    {
      const f16* qrow = q16 + (size_t)(b * NT + trow) * 256;
#pragma unroll
      for (int kf = 0; kf < 8; ++kf)
        aq[kf] = *(const half8*)(qrow + kf * 32 + q * 8);
    }
    f32x4 xT[4];
#pragma unroll
    for (int i = 0; i < 4; ++i) xT[i] = (f32x4){0.f, 0.f, 0.f, 0.f};
    __builtin_amdgcn_s_setprio(1);  // T5
#pragma unroll
    for (int kf = 0; kf < 8; ++kf)
#pragma unroll
      for (int nb = 0; nb < 4; ++nb) {
        const int rs = nb * 16 + lc;
        half8 mbf = *(const half8*)((const char*)Bs + rs * 512 + swz(rs, kf * 64 + q * 16));
        xT[nb] = MFMA16(mbf, aq[kf], xT[nb]);
      }
    __builtin_amdgcn_s_setprio(0);
    float v[4][4];
    float vmax = NEGBIG;
#pragma unroll
    for (int nb = 0; nb < 4; ++nb) {
      v[nb][0] = mk[nb].x ? xT[nb][0] : NEGBIG;
      v[nb][1] = mk[nb].y ? xT[nb][1] : NEGBIG;
      v[nb][2] = mk[nb].z ? xT[nb][2] : NEGBIG;
      v[nb][3] = mk[nb].w ? xT[nb][3] : NEGBIG;
      vmax = fmaxf(vmax, fmaxf(fmaxf(v[nb][0], v[nb][1]), fmaxf(v[nb][2], v[nb][3])));
    }
    vmax = fmaxf(vmax, __shfl_xor(vmax, 16));
    vmax = fmaxf(vmax, __shfl_xor(vmax, 32));
    float vsum = 0.f;
    if (xh16) {
      f16* xr = xh16 + (size_t)(b * NT + trow) * NS + s0;
#pragma unroll
      for (int nb = 0; nb < 4; ++nb) {
        float e0 = __expf(v[nb][0] - vmax), e1 = __expf(v[nb][1] - vmax);
        float e2 = __expf(v[nb][2] - vmax), e3 = __expf(v[nb][3] - vmax);
        vsum += e0 + e1 + e2 + e3;
        half4v hv = {(f16)e0, (f16)e1, (f16)e2, (f16)e3};
        *(half4v*)(xr + nb * 16 + q * 4) = hv;
      }
    } else {
      float* ab = alignv + ((size_t)b * NT + trow) * NS + s0;
#pragma unroll
      for (int nb = 0; nb < 4; ++nb) {
        *(f32x4*)(ab + nb * 16 + q * 4) = (f32x4){v[nb][0], v[nb][1], v[nb][2], v[nb][3]};
        vsum += __expf(v[nb][0] - vmax) + __expf(v[nb][1] - vmax) +
                __expf(v[nb][2] - vmax) + __expf(v[nb][3] - vmax);
      }
    }
    vsum += __shfl_xor(vsum, 16);
    vsum += __shfl_xor(vsum, 32);
    if (l < 16) {
      pstats[((size_t)(b * NT + trow) * 64 + kc) * 2 + 0] = vmax;
      pstats[((size_t)(b * NT + trow) * 64 + kc) * 2 + 1] = vsum;
    }
  }
}

// ---------------- K3: p ; partial c = P@V + fused row-stats + setprio ----
__global__ __launch_bounds__(512, 4) void k_pv(const float* __restrict__ mbank,
                                               const float* __restrict__ pstats,
                                               float* __restrict__ alignv,
                                               f16* __restrict__ pc,
                                               const f16* __restrict__ xh16) {
  __shared__ __align__(16) f16 VT[256 * 64];
  __shared__ __align__(16) f16 Ps[64 * 64];
  const int tid = threadIdx.x;
  const int w = tid >> 6, l = tid & 63;
  const int wtg = w >> 2, wd = w & 3;
  const int q = l >> 4, lc = l & 15;
  const int bid = blockIdx.x;
  const int b = bid & 7;
  const int kc = (bid >> 3) & 3;
  const int tt = bid >> 5;
  const int t0 = tt * 64;
  const int s0 = kc * 1024;

  const int pt = tid >> 3;
  const int ps8 = (tid & 7) * 8;
  const size_t rowg = (size_t)b * NT + t0 + pt;

  // fused row-stats: 8 threads per row reduce 64 chunk partials
  float mv, lv;
  {
    const float* pr = pstats + (rowg * 64 + (size_t)(tid & 7) * 8) * 2;
    float4 a0 = ((const float4*)pr)[0];
    float4 a1 = ((const float4*)pr)[1];
    float4 a2 = ((const float4*)pr)[2];
    float4 a3 = ((const float4*)pr)[3];
    float mloc = fmaxf(fmaxf(a0.x, a0.z), fmaxf(a1.x, a1.z));
    mloc = fmaxf(mloc, fmaxf(fmaxf(a2.x, a2.z), fmaxf(a3.x, a3.z)));
    mloc = fmaxf(mloc, __shfl_xor(mloc, 1));
    mloc = fmaxf(mloc, __shfl_xor(mloc, 2));
    mloc = fmaxf(mloc, __shfl_xor(mloc, 4));
    float s = a0.y * __expf(a0.x - mloc) + a0.w * __expf(a0.z - mloc) +
              a1.y * __expf(a1.x - mloc) + a1.w * __expf(a1.z - mloc) +
              a2.y * __expf(a2.x - mloc) + a2.w * __expf(a2.z - mloc) +
              a3.y * __expf(a3.x - mloc) + a3.w * __expf(a3.z - mloc);
    s += __shfl_xor(s, 1);
    s += __shfl_xor(s, 2);
    s += __shfl_xor(s, 4);
    mv = mloc;
    lv = (s > 0.f) ? (1.f / s) : 0.f;
  }

  float* xrow = alignv + rowg * NS + s0 + ps8;
  const f16* hrow = xh16 ? (xh16 + rowg * NS + s0 + ps8) : nullptr;
  const float* prow = pstats + (rowg * 64 + kc * 16) * 2;

  f32x4 acc[2][4];
#pragma unroll
  for (int i = 0; i < 2; ++i)
#pragma unroll
    for (int j = 0; j < 4; ++j) acc[i][j] = (f32x4){0.f, 0.f, 0.f, 0.f};

  const int dstage = (w & 3) * 64 + l;
  const int shalf = (w >> 2) * 32;

  float4 xA, xB;
  half8 hx;
  if (xh16) {
    hx = *(const half8*)(hrow);
  } else {
    xA = ((const float4*)xrow)[0];
    xB = ((const float4*)xrow)[1];
  }

  for (int st = 0; st < 16; ++st) {
    const int sb = s0 + st * 64;
    __syncthreads();
    {
#pragma unroll
      for (int i = 0; i < 8; ++i) {
        const int s4 = shalf + i * 4;
        const float* g = mbank + ((size_t)b * NS + sb + s4) * ND + dstage;
        const float f0 = g[0], f1 = g[ND], f2 = g[2 * ND], f3 = g[3 * ND];
        half4v h = {(f16)f0, (f16)f1, (f16)f2, (f16)f3};
        *(half4v*)((char*)VT + dstage * 128 + swz(dstage, s4 * 2)) = h;
      }
    }
    {
      float p0, p1, p2, p3, p4, p5, p6, p7;
      if (xh16) {
        const float scale = __expf(prow[st * 2] - mv) * lv;
        p0 = (float)hx[0] * scale; p1 = (float)hx[1] * scale;
        p2 = (float)hx[2] * scale; p3 = (float)hx[3] * scale;
        p4 = (float)hx[4] * scale; p5 = (float)hx[5] * scale;
        p6 = (float)hx[6] * scale; p7 = (float)hx[7] * scale;
      } else {
        p0 = __expf(xA.x - mv) * lv; p1 = __expf(xA.y - mv) * lv;
        p2 = __expf(xA.z - mv) * lv; p3 = __expf(xA.w - mv) * lv;
        p4 = __expf(xB.x - mv) * lv; p5 = __expf(xB.y - mv) * lv;
        p6 = __expf(xB.z - mv) * lv; p7 = __expf(xB.w - mv) * lv;
      }
      float* xp = xrow + st * 64;
      f32x4 s0v = {p0, p1, p2, p3};
      f32x4 s1v = {p4, p5, p6, p7};
      __builtin_nontemporal_store(s0v, (f32x4*)xp);
      __builtin_nontemporal_store(s1v, (f32x4*)(xp + 4));
      half8 h = {(f16)p0, (f16)p1, (f16)p2, (f16)p3,
                 (f16)p4, (f16)p5, (f16)p6, (f16)p7};
      *(half8*)((char*)Ps + pt * 128 + swz(pt, ps8 * 2)) = h;
    }
    if (st < 15) {
      if (xh16) {
        hx = *(const half8*)(hrow + (st + 1) * 64);
      } else {
        const float* xn = xrow + (st + 1) * 64;
        xA = ((const float4*)xn)[0];
        xB = ((const float4*)xn)[1];
      }
    }
    __syncthreads();
    half8 a[2][2];
#pragma unroll
    for (int mb = 0; mb < 2; ++mb)
#pragma unroll
      for (int kf = 0; kf < 2; ++kf) {
        const int r = wtg * 32 + mb * 16 + lc;
        a[mb][kf] = *(const half8*)((const char*)Ps + r * 128 + swz(r, kf * 64 + q * 16));
      }
    __builtin_amdgcn_s_setprio(1);  // T5
#pragma unroll
    for (int kf = 0; kf < 2; ++kf)
#pragma unroll
      for (int nb = 0; nb < 4; ++nb) {
        const int d = wd * 64 + nb * 16 + lc;
        half8 bbt = *(const half8*)((const char*)VT + d * 128 + swz(d, kf * 64 + q * 16));
#pragma unroll
        for (int mb = 0; mb < 2; ++mb)
          acc[mb][nb] = MFMA16(a[mb][kf], bbt, acc[mb][nb]);
      }
    __builtin_amdgcn_s_setprio(0);
  }

#pragma unroll
  for (int mb = 0; mb < 2; ++mb)
#pragma unroll
    for (int nb = 0; nb < 4; ++nb)
#pragma unroll
      for (int j = 0; j < 4; ++j) {
        const int t = t0 + wtg * 32 + mb * 16 + q * 4 + j;
        const int d = wd * 64 + nb * 16 + lc;
        pc[(size_t)kc * ((size_t)NBATCH * NT * ND) + ((size_t)b * NT + t) * ND + d] =
            (f16)acc[mb][nb][j];
      }
}

// ---------------- K4: c = sum of 4 fp16 split-K partials ----------------
__global__ __launch_bounds__(256) void k_csum(const f16* __restrict__ pc,
                                              float* __restrict__ outc) {
  const size_t i8 = ((size_t)blockIdx.x * 256 + threadIdx.x) * 8;
  const size_t STRIDE = (size_t)NBATCH * NT * ND;
  half8 a = *(const half8*)(pc + i8);
  half8 b = *(const half8*)(pc + STRIDE + i8);
  half8 c = *(const half8*)(pc + 2 * STRIDE + i8);
  half8 d = *(const half8*)(pc + 3 * STRIDE + i8);
  float4 r0, r1;
  r0.x = (float)a[0] + (float)b[0] + (float)c[0] + (float)d[0];
  r0.y = (float)a[1] + (float)b[1] + (float)c[1] + (float)d[1];
  r0.z = (float)a[2] + (float)b[2] + (float)c[2] + (float)d[2];
  r0.w = (float)a[3] + (float)b[3] + (float)c[3] + (float)d[3];
  r1.x = (float)a[4] + (float)b[4] + (float)c[4] + (float)d[4];
  r1.y = (float)a[5] + (float)b[5] + (float)c[5] + (float)d[5];
  r1.z = (float)a[6] + (float)b[6] + (float)c[6] + (float)d[6];
  r1.w = (float)a[7] + (float)b[7] + (float)c[7] + (float)d[7];
  *(float4*)(outc + i8) = r0;
  *(float4*)(outc + i8 + 4) = r1;
}

extern "C" void kernel_launch(void* const* d_in, const int* in_sizes, int n_in,
                              void* d_out, int out_size, void* d_ws, size_t ws_size,
                              hipStream_t stream) {
  const float* mbank = (const float*)d_in[0];  // (8,4096,256) f32
  const float* src   = (const float*)d_in[1];  // (8,1024,256) f32
  const int*   mask  = (const int*)d_in[2];    // (8,4096) bool->int
  const float* W     = (const float*)d_in[3];  // (256,256) f32

  float* out_c = (float*)d_out;
  float* out_align = out_c + (size_t)NBATCH * NT * ND;

  // ws layout:
  //   [0, 4 MB)          q16   : 8192x256 fp16
  //   [4 MB, 8 MB)       pstats: 8192x64x2 f32
  //   [8 MB, 24 MB)      pc    : 4 x 2M fp16 split-K partials
  //   [28 MB, 92 MB)     xh    : fp16 chunk-exponentials (if ws fits)
  char* ws = (char*)d_ws;
  f16* q16      = (f16*)ws;
  float* pstats = (float*)(ws + (4 << 20));
  f16* pc       = (f16*)(ws + (8 << 20));
  f16* xh16 = (ws_size >= ((size_t)92 << 20)) ? (f16*)(ws + (28 << 20)) : nullptr;

  hipLaunchKernelGGL(k_qproj, dim3(128), dim3(256), 0, stream, src, W, q16);
  hipLaunchKernelGGL(k_logits7, dim3(512), dim3(512), 0, stream,
                     mbank, q16, mask, out_align, pstats, xh16);
  hipLaunchKernelGGL(k_pv, dim3(512), dim3(512), 0, stream,
                     mbank, pstats, out_align, pc, (const f16*)xh16);
  hipLaunchKernelGGL(k_csum, dim3(1024), dim3(256), 0, stream, pc, out_c);
}